// Round 8
// baseline (202.796 us; speedup 1.0000x reference)
//
#include <hip/hip_runtime.h>

constexpr int FIN    = 128;
constexpr int LOG_RB = 7;
constexpr int RB     = 1 << LOG_RB;   // 128 nodes per bucket
constexpr int BMAX   = 1024;
constexpr int CAP    = 4096;          // arena slots per bucket (avg load ~2046, sd ~45)
constexpr int CHUNK  = 16384;         // edges per bucket_scatter block (write clustering)

typedef _Float16 half8 __attribute__((ext_vector_type(8)));
typedef float    f32x4 __attribute__((ext_vector_type(4)));

// ================= arena init: gcur[b] = b*CAP =================
__global__ __launch_bounds__(1024) void init_gcur_kernel(int* __restrict__ gcur, int B) {
    int i = blockIdx.x * 1024 + threadIdx.x;
    if (i < B) gcur[i] = i * CAP;
}

// ====== bucket scatter into per-bucket arena ================================
__global__ __launch_bounds__(256) void bucket_scatter_kernel(
    const int* __restrict__ src, const int* __restrict__ dst,
    int* __restrict__ gcur, unsigned* __restrict__ gEdges, int E, int B)
{
    __shared__ int lhist[BMAX];
    __shared__ int lbase[BMAX];
    __shared__ int lcur[BMAX];
    const int e0 = blockIdx.x * CHUNK;
    const int e1 = min(e0 + CHUNK, E);
    for (int i = threadIdx.x; i < B; i += 256) { lhist[i] = 0; lcur[i] = 0; }
    __syncthreads();
    for (int e = e0 + threadIdx.x; e < e1; e += 256)
        atomicAdd(&lhist[dst[e] >> LOG_RB], 1);
    __syncthreads();
    for (int i = threadIdx.x; i < B; i += 256) {
        int c = lhist[i];
        if (c) lbase[i] = atomicAdd(&gcur[i], c);
    }
    __syncthreads();
    for (int e = e0 + threadIdx.x; e < e1; e += 256) {
        int d = dst[e];
        int b = d >> LOG_RB;
        int pos = lbase[b] + atomicAdd(&lcur[b], 1);
        if (pos < (b + 1) * CAP)   // capacity clamp
            gEdges[pos] = ((unsigned)src[e] << LOG_RB) | (unsigned)(d & (RB - 1));
    }
}

// ====== finalize: per bucket -> rbeg/rend, dis, esrc (LDS-staged edges) =====
__global__ __launch_bounds__(256) void finalize_kernel(
    const unsigned* __restrict__ gEdges, const int* __restrict__ gcur,
    int* __restrict__ rbeg, int* __restrict__ rend, float* __restrict__ dis,
    int* __restrict__ esrc, int N)
{
    __shared__ int h[RB];
    __shared__ int excl[RB];
    __shared__ int cur[RB];
    __shared__ unsigned sedge[CAP];            // 16 KB stage
    const int b = blockIdx.x;
    const int base = b * CAP;
    int cnt = gcur[b] - base;
    if (cnt > CAP) cnt = CAP;
    const int node0 = b << LOG_RB;
    if (threadIdx.x < RB) h[threadIdx.x] = 0;
    __syncthreads();
    for (int i = threadIdx.x; i < cnt; i += 256) {
        unsigned p = gEdges[base + i];
        sedge[i] = p;
        atomicAdd(&h[p & (RB - 1)], 1);
    }
    __syncthreads();
    if (threadIdx.x < RB) excl[threadIdx.x] = h[threadIdx.x];
    __syncthreads();
    for (int off = 1; off < RB; off <<= 1) {
        int u = 0;
        if (threadIdx.x < RB && threadIdx.x >= off) u = excl[threadIdx.x - off];
        __syncthreads();
        if (threadIdx.x < RB) excl[threadIdx.x] += u;
        __syncthreads();
    }
    if (threadIdx.x < RB) {
        int c  = h[threadIdx.x];
        int ex = excl[threadIdx.x] - c;
        cur[threadIdx.x] = ex;
        int node = node0 + threadIdx.x;
        if (node < N) {
            rbeg[node] = base + ex;
            rend[node] = base + ex + c;
            dis[node]  = c > 0 ? rsqrtf((float)c) : 0.0f;
        }
    }
    __syncthreads();
    for (int i = threadIdx.x; i < cnt; i += 256) {
        unsigned p = sedge[i];
        int dl = (int)(p & (RB - 1));
        int pos = base + atomicAdd(&cur[dl], 1);
        esrc[pos] = (int)(p >> LOG_RB);
    }
}

// ====== linear1: h1(f16) = dis[n]*(X(f32) @ W1^T + b1), MFMA, packed stores =
__global__ __launch_bounds__(256) void linear1_kernel(
    const float* __restrict__ X, const float* __restrict__ W,
    const float* __restrict__ Bv, const float* __restrict__ dis,
    _Float16* __restrict__ Y, int N)
{
    __shared__ __align__(16) _Float16 xs[64 * 128];   // 16 KB
    const int tid  = threadIdx.x;
    const int wave = tid >> 6;
    const int lane = tid & 63;
    const int l15  = lane & 15;
    const int lhi  = lane >> 4;

    half8 wf[2][4];
    float bias[2];
    #pragma unroll
    for (int c = 0; c < 2; ++c) {
        int f = (wave * 2 + c) * 16 + l15;
        #pragma unroll
        for (int ks = 0; ks < 4; ++ks) {
            const float* wp = &W[f * 128 + ks * 32 + lhi * 8];
            float4 u0 = *(const float4*)wp;
            float4 u1 = *(const float4*)(wp + 4);
            half8 hh;
            hh[0] = (_Float16)u0.x; hh[1] = (_Float16)u0.y;
            hh[2] = (_Float16)u0.z; hh[3] = (_Float16)u0.w;
            hh[4] = (_Float16)u1.x; hh[5] = (_Float16)u1.y;
            hh[6] = (_Float16)u1.z; hh[7] = (_Float16)u1.w;
            wf[c][ks] = hh;
        }
        bias[c] = Bv[f];
    }

    const int nchunks = (N + 63) / 64;
    for (int ch = blockIdx.x; ch < nchunks; ch += gridDim.x) {
        const int n0 = ch * 64;
        __syncthreads();
        #pragma unroll
        for (int p = 0; p < 4; ++p) {
            int ci  = p * 256 + tid;
            int row = ci >> 4, c = ci & 15;
            int n   = n0 + row;
            int nc  = n < N ? n : N - 1;
            const float* xp = &X[(size_t)nc * 128 + c * 8];
            float4 u0 = *(const float4*)xp;
            float4 u1 = *(const float4*)(xp + 4);
            half8 hh;
            hh[0] = (_Float16)u0.x; hh[1] = (_Float16)u0.y;
            hh[2] = (_Float16)u0.z; hh[3] = (_Float16)u0.w;
            hh[4] = (_Float16)u1.x; hh[5] = (_Float16)u1.y;
            hh[6] = (_Float16)u1.z; hh[7] = (_Float16)u1.w;
            *(half8*)&xs[row * 128 + (c ^ (row & 7)) * 8] = hh;
        }
        __syncthreads();

        f32x4 acc[4][2];
        #pragma unroll
        for (int mt = 0; mt < 4; ++mt)
            #pragma unroll
            for (int c = 0; c < 2; ++c) {
                acc[mt][c][0] = bias[c]; acc[mt][c][1] = bias[c];
                acc[mt][c][2] = bias[c]; acc[mt][c][3] = bias[c];
            }

        #pragma unroll
        for (int mt = 0; mt < 4; ++mt) {
            int row = mt * 16 + l15;
            #pragma unroll
            for (int ks = 0; ks < 4; ++ks) {
                int c  = ks * 4 + lhi;
                half8 a = *(const half8*)&xs[row * 128 + (c ^ (row & 7)) * 8];
                #pragma unroll
                for (int c2 = 0; c2 < 2; ++c2)
                    acc[mt][c2] = __builtin_amdgcn_mfma_f32_16x16x32_f16(
                        a, wf[c2][ks], acc[mt][c2], 0, 0, 0);
            }
        }
        __syncthreads();   // xs reads done; repack output into xs (linear)
        #pragma unroll
        for (int mt = 0; mt < 4; ++mt)
            #pragma unroll
            for (int r = 0; r < 4; ++r) {
                int row = mt * 16 + lhi * 4 + r;
                int n   = n0 + row;
                int nc  = n < N ? n : N - 1;
                float dv = dis[nc];
                #pragma unroll
                for (int c2 = 0; c2 < 2; ++c2) {
                    int col = (wave * 2 + c2) * 16 + l15;
                    xs[row * 128 + col] = (_Float16)(dv * acc[mt][c2][r]);
                }
            }
        __syncthreads();
        #pragma unroll
        for (int p = 0; p < 4; ++p) {
            int ci  = p * 256 + tid;
            int row = ci >> 4, c = ci & 15;
            int n   = n0 + row;
            if (n < N)
                *(half8*)&Y[(size_t)n * 128 + c * 8] = *(const half8*)&xs[row * 128 + c * 8];
        }
    }
}

// ====== layer-1 aggregate: agg1(f16) = relu(dis[d]*sum h1'[src]) ============
// unroll-4 + software-pipelined esrc prefetch (break idx->gather serial chain)
__global__ __launch_bounds__(256) void aggregate128h_kernel(
    const _Float16* __restrict__ H, const int* __restrict__ rbeg,
    const int* __restrict__ rend, const int* __restrict__ esrc,
    const float* __restrict__ dis, _Float16* __restrict__ OUT, int N)
{
    const int lane = threadIdx.x & 15;
    const int d = blockIdx.x * 16 + (threadIdx.x >> 4);
    if (d >= N) return;
    const int beg = rbeg[d], end = rend[d];
    float acc[4][8];
    #pragma unroll
    for (int u = 0; u < 4; ++u)
        #pragma unroll
        for (int j = 0; j < 8; ++j) acc[u][j] = 0.0f;

    const int n4 = (end - beg) >> 2;
    int e = beg;
    if (n4 > 0) {
        int s0 = esrc[e], s1 = esrc[e+1], s2 = esrc[e+2], s3 = esrc[e+3];
        for (int q = 1; q < n4; ++q) {
            const int b2 = beg + q * 4;
            int t0 = esrc[b2], t1 = esrc[b2+1], t2 = esrc[b2+2], t3 = esrc[b2+3];
            half8 v0 = *(const half8*)&H[(size_t)s0 * 128 + lane * 8];
            half8 v1 = *(const half8*)&H[(size_t)s1 * 128 + lane * 8];
            half8 v2 = *(const half8*)&H[(size_t)s2 * 128 + lane * 8];
            half8 v3 = *(const half8*)&H[(size_t)s3 * 128 + lane * 8];
            #pragma unroll
            for (int j = 0; j < 8; ++j) {
                acc[0][j] += (float)v0[j]; acc[1][j] += (float)v1[j];
                acc[2][j] += (float)v2[j]; acc[3][j] += (float)v3[j];
            }
            s0 = t0; s1 = t1; s2 = t2; s3 = t3;
        }
        {
            half8 v0 = *(const half8*)&H[(size_t)s0 * 128 + lane * 8];
            half8 v1 = *(const half8*)&H[(size_t)s1 * 128 + lane * 8];
            half8 v2 = *(const half8*)&H[(size_t)s2 * 128 + lane * 8];
            half8 v3 = *(const half8*)&H[(size_t)s3 * 128 + lane * 8];
            #pragma unroll
            for (int j = 0; j < 8; ++j) {
                acc[0][j] += (float)v0[j]; acc[1][j] += (float)v1[j];
                acc[2][j] += (float)v2[j]; acc[3][j] += (float)v3[j];
            }
        }
        e = beg + n4 * 4;
    }
    for (; e < end; ++e) {
        int s0 = esrc[e];
        half8 v0 = *(const half8*)&H[(size_t)s0 * 128 + lane * 8];
        #pragma unroll
        for (int j = 0; j < 8; ++j) acc[0][j] += (float)v0[j];
    }
    float w = dis[d];
    half8 o;
    #pragma unroll
    for (int j = 0; j < 8; ++j) {
        float t = w * ((acc[0][j] + acc[1][j]) + (acc[2][j] + acc[3][j]));
        o[j] = (_Float16)fmaxf(t, 0.0f);          // relu
    }
    *(half8*)&OUT[(size_t)d * 128 + lane * 8] = o;
}

// ====== lin2: h2(f16) = dis[n]*(agg1(f16) @ W2^T + b2), MFMA, packed stores =
__global__ __launch_bounds__(256) void lin2_kernel(
    const _Float16* __restrict__ Xh, const float* __restrict__ W,
    const float* __restrict__ Bv, const float* __restrict__ dis,
    _Float16* __restrict__ Y, int N)
{
    __shared__ __align__(16) _Float16 xs[64 * 128];   // 16 KB in, 8 KB reused out
    const int tid  = threadIdx.x;
    const int wave = tid >> 6;
    const int lane = tid & 63;
    const int l15  = lane & 15;
    const int lhi  = lane >> 4;

    half8 wf[4];
    float bias;
    {
        int f = wave * 16 + l15;
        #pragma unroll
        for (int ks = 0; ks < 4; ++ks) {
            const float* wp = &W[f * 128 + ks * 32 + lhi * 8];
            float4 u0 = *(const float4*)wp;
            float4 u1 = *(const float4*)(wp + 4);
            half8 hh;
            hh[0] = (_Float16)u0.x; hh[1] = (_Float16)u0.y;
            hh[2] = (_Float16)u0.z; hh[3] = (_Float16)u0.w;
            hh[4] = (_Float16)u1.x; hh[5] = (_Float16)u1.y;
            hh[6] = (_Float16)u1.z; hh[7] = (_Float16)u1.w;
            wf[ks] = hh;
        }
        bias = Bv[f];
    }

    const int nchunks = (N + 63) / 64;
    for (int ch = blockIdx.x; ch < nchunks; ch += gridDim.x) {
        const int n0 = ch * 64;
        __syncthreads();
        #pragma unroll
        for (int p = 0; p < 4; ++p) {
            int ci  = p * 256 + tid;
            int row = ci >> 4, c = ci & 15;
            int n   = n0 + row;
            int nc  = n < N ? n : N - 1;
            half8 hh = *(const half8*)&Xh[(size_t)nc * 128 + c * 8];
            *(half8*)&xs[row * 128 + (c ^ (row & 7)) * 8] = hh;
        }
        __syncthreads();

        f32x4 acc[4];
        #pragma unroll
        for (int mt = 0; mt < 4; ++mt) {
            acc[mt][0] = bias; acc[mt][1] = bias;
            acc[mt][2] = bias; acc[mt][3] = bias;
        }
        #pragma unroll
        for (int mt = 0; mt < 4; ++mt) {
            int row = mt * 16 + l15;
            #pragma unroll
            for (int ks = 0; ks < 4; ++ks) {
                int c  = ks * 4 + lhi;
                half8 a = *(const half8*)&xs[row * 128 + (c ^ (row & 7)) * 8];
                acc[mt] = __builtin_amdgcn_mfma_f32_16x16x32_f16(a, wf[ks], acc[mt], 0, 0, 0);
            }
        }
        __syncthreads();   // reuse xs as [64][64] output tile
        #pragma unroll
        for (int mt = 0; mt < 4; ++mt)
            #pragma unroll
            for (int r = 0; r < 4; ++r) {
                int row = mt * 16 + lhi * 4 + r;
                int n   = n0 + row;
                int nc  = n < N ? n : N - 1;
                float dv = dis[nc];
                xs[row * 64 + wave * 16 + l15] = (_Float16)(dv * acc[mt][r]);
            }
        __syncthreads();
        #pragma unroll
        for (int p = 0; p < 2; ++p) {
            int ci  = p * 256 + tid;
            int row = ci >> 3, c = ci & 7;
            int n   = n0 + row;
            if (n < N)
                *(half8*)&Y[(size_t)n * 64 + c * 8] = *(const half8*)&xs[row * 64 + c * 8];
        }
    }
}

// ====== layer-2 aggregate: out(f32) = dis[d]*sum h2'[src], pipelined ========
__global__ __launch_bounds__(256) void aggregate64h_kernel(
    const _Float16* __restrict__ H, const int* __restrict__ rbeg,
    const int* __restrict__ rend, const int* __restrict__ esrc,
    const float* __restrict__ dis, float* __restrict__ OUT, int N)
{
    const int lane = threadIdx.x & 7;
    const int d = blockIdx.x * 32 + (threadIdx.x >> 3);
    if (d >= N) return;
    const int beg = rbeg[d], end = rend[d];
    float acc[4][8];
    #pragma unroll
    for (int u = 0; u < 4; ++u)
        #pragma unroll
        for (int j = 0; j < 8; ++j) acc[u][j] = 0.0f;

    const int n4 = (end - beg) >> 2;
    int e = beg;
    if (n4 > 0) {
        int s0 = esrc[e], s1 = esrc[e+1], s2 = esrc[e+2], s3 = esrc[e+3];
        for (int q = 1; q < n4; ++q) {
            const int b2 = beg + q * 4;
            int t0 = esrc[b2], t1 = esrc[b2+1], t2 = esrc[b2+2], t3 = esrc[b2+3];
            half8 v0 = *(const half8*)&H[(size_t)s0 * 64 + lane * 8];
            half8 v1 = *(const half8*)&H[(size_t)s1 * 64 + lane * 8];
            half8 v2 = *(const half8*)&H[(size_t)s2 * 64 + lane * 8];
            half8 v3 = *(const half8*)&H[(size_t)s3 * 64 + lane * 8];
            #pragma unroll
            for (int j = 0; j < 8; ++j) {
                acc[0][j] += (float)v0[j]; acc[1][j] += (float)v1[j];
                acc[2][j] += (float)v2[j]; acc[3][j] += (float)v3[j];
            }
            s0 = t0; s1 = t1; s2 = t2; s3 = t3;
        }
        {
            half8 v0 = *(const half8*)&H[(size_t)s0 * 64 + lane * 8];
            half8 v1 = *(const half8*)&H[(size_t)s1 * 64 + lane * 8];
            half8 v2 = *(const half8*)&H[(size_t)s2 * 64 + lane * 8];
            half8 v3 = *(const half8*)&H[(size_t)s3 * 64 + lane * 8];
            #pragma unroll
            for (int j = 0; j < 8; ++j) {
                acc[0][j] += (float)v0[j]; acc[1][j] += (float)v1[j];
                acc[2][j] += (float)v2[j]; acc[3][j] += (float)v3[j];
            }
        }
        e = beg + n4 * 4;
    }
    for (; e < end; ++e) {
        int s0 = esrc[e];
        half8 v0 = *(const half8*)&H[(size_t)s0 * 64 + lane * 8];
        #pragma unroll
        for (int j = 0; j < 8; ++j) acc[0][j] += (float)v0[j];
    }
    float w = dis[d];
    float4 o0, o1;
    o0.x = w * ((acc[0][0] + acc[1][0]) + (acc[2][0] + acc[3][0]));
    o0.y = w * ((acc[0][1] + acc[1][1]) + (acc[2][1] + acc[3][1]));
    o0.z = w * ((acc[0][2] + acc[1][2]) + (acc[2][2] + acc[3][2]));
    o0.w = w * ((acc[0][3] + acc[1][3]) + (acc[2][3] + acc[3][3]));
    o1.x = w * ((acc[0][4] + acc[1][4]) + (acc[2][4] + acc[3][4]));
    o1.y = w * ((acc[0][5] + acc[1][5]) + (acc[2][5] + acc[3][5]));
    o1.z = w * ((acc[0][6] + acc[1][6]) + (acc[2][6] + acc[3][6]));
    o1.w = w * ((acc[0][7] + acc[1][7]) + (acc[2][7] + acc[3][7]));
    float* p = &OUT[(size_t)d * 64 + lane * 8];
    *(float4*)p = o0;
    *(float4*)(p + 4) = o1;
}

// ================= fallback path (round-1, f32 end-to-end) ==================
template <int FOUT, bool RELU_IN>
__global__ __launch_bounds__(256) void linear_kernel(
    const float* __restrict__ X, const float* __restrict__ W,
    const float* __restrict__ Bv, float* __restrict__ Y, int N)
{
    constexpr int TX = FOUT / 4;
    constexpr int TY = 256 / TX;
    constexpr int NB = 4 * TY;
    constexpr int QMASK = TX - 1;
    __shared__ float ws[FIN * FOUT];
    __shared__ float xs[NB * FIN];
    const int tid = threadIdx.x;
    const int tx  = tid % TX;
    const int ty  = tid / TX;
    for (int i = tid; i < FOUT * FIN; i += 256) {
        int f = i >> 7;
        int k = i & (FIN - 1);
        int q = f >> 2, r = f & 3;
        int qq = q ^ (k & QMASK);
        ws[k * FOUT + qq * 4 + r] = W[i];
    }
    const float4 bv = *(const float4*)&Bv[tx * 4];
    const int nchunks = (N + NB - 1) / NB;
    for (int c = blockIdx.x; c < nchunks; c += gridDim.x) {
        const int n0 = c * NB;
        __syncthreads();
        constexpr int V4 = FIN / 4;
        for (int i4 = tid; i4 < NB * V4; i4 += 256) {
            int row = i4 / V4, c4 = i4 % V4;
            int n = n0 + row;
            int nc = n < N ? n : N - 1;
            float4 v = *(const float4*)&X[(long long)nc * FIN + c4 * 4];
            if (RELU_IN) {
                v.x = fmaxf(v.x, 0.0f); v.y = fmaxf(v.y, 0.0f);
                v.z = fmaxf(v.z, 0.0f); v.w = fmaxf(v.w, 0.0f);
            }
            *(float4*)&xs[row * FIN + c4 * 4] = v;
        }
        __syncthreads();
        float acc[4][4];
        #pragma unroll
        for (int j = 0; j < 4; ++j) {
            acc[j][0] = bv.x; acc[j][1] = bv.y; acc[j][2] = bv.z; acc[j][3] = bv.w;
        }
        #pragma unroll 2
        for (int k = 0; k < FIN; k += 4) {
            float w[4][4];
            #pragma unroll
            for (int kk = 0; kk < 4; ++kk) {
                int kr = k + kk;
                float4 t = *(const float4*)&ws[kr * FOUT + ((tx ^ (kr & QMASK)) << 2)];
                w[kk][0] = t.x; w[kk][1] = t.y; w[kk][2] = t.z; w[kk][3] = t.w;
            }
            float xr[4][4];
            #pragma unroll
            for (int j = 0; j < 4; ++j) {
                float4 t = *(const float4*)&xs[(ty * 4 + j) * FIN + k];
                xr[j][0] = t.x; xr[j][1] = t.y; xr[j][2] = t.z; xr[j][3] = t.w;
            }
            #pragma unroll
            for (int j = 0; j < 4; ++j)
                #pragma unroll
                for (int kk = 0; kk < 4; ++kk) {
                    acc[j][0] = fmaf(xr[j][kk], w[kk][0], acc[j][0]);
                    acc[j][1] = fmaf(xr[j][kk], w[kk][1], acc[j][1]);
                    acc[j][2] = fmaf(xr[j][kk], w[kk][2], acc[j][2]);
                    acc[j][3] = fmaf(xr[j][kk], w[kk][3], acc[j][3]);
                }
        }
        #pragma unroll
        for (int j = 0; j < 4; ++j) {
            int n = n0 + ty * 4 + j;
            if (n < N) {
                float4 o;
                o.x = acc[j][0]; o.y = acc[j][1]; o.z = acc[j][2]; o.w = acc[j][3];
                *(float4*)&Y[(long long)n * FOUT + tx * 4] = o;
            }
        }
    }
}

template <int LOGF>
__global__ __launch_bounds__(256) void scatter_kernel(
    const float* __restrict__ H, const int* __restrict__ src,
    const int* __restrict__ dst, const float* __restrict__ dis,
    float* __restrict__ OUT, int E)
{
    constexpr int F = 1 << LOGF;
    const long long total  = (long long)E << LOGF;
    const long long stride = (long long)gridDim.x * blockDim.x;
    for (long long i = (long long)blockIdx.x * blockDim.x + threadIdx.x;
         i < total; i += stride) {
        int e = (int)(i >> LOGF);
        int f = (int)i & (F - 1);
        int s = src[e];
        int d = dst[e];
        float w = dis[s] * dis[d];
        atomicAdd(&OUT[d * F + f], w * H[s * F + f]);
    }
}

__global__ __launch_bounds__(256) void dis_inplace_kernel(float* __restrict__ deg, int N) {
    int i = blockIdx.x * 256 + threadIdx.x;
    if (i < N) {
        float d = deg[i];
        deg[i] = d > 0.0f ? rsqrtf(d) : 0.0f;
    }
}

__global__ __launch_bounds__(256) void deg_kernel_f(const int* __restrict__ dst,
                                                    float* __restrict__ deg, int E) {
    int stride = gridDim.x * 256;
    for (int i = blockIdx.x * 256 + threadIdx.x; i < E; i += stride)
        atomicAdd(&deg[dst[i]], 1.0f);
}

static inline size_t align512(size_t x) { return (x + 511) & ~(size_t)511; }

extern "C" void kernel_launch(void* const* d_in, const int* in_sizes, int n_in,
                              void* d_out, int out_size, void* d_ws, size_t ws_size,
                              hipStream_t stream)
{
    const float* x  = (const float*)d_in[0];
    const int*   ei = (const int*)d_in[1];
    const float* W1 = (const float*)d_in[2];
    const float* b1 = (const float*)d_in[3];
    const float* W2 = (const float*)d_in[4];
    const float* b2 = (const float*)d_in[5];

    const int N = in_sizes[0] / FIN;     // 100000
    const int E = in_sizes[1] / 2;       // 1600000
    const int* src = ei;
    const int* dst = ei + E;
    float* out = (float*)d_out;
    char* wsb = (char*)d_ws;

    const int B = (N + RB - 1) / RB;     // 782

    // ---- workspace layout ----
    size_t hreg = (size_t)N * 128 * 2;                       // h1 region (fp16)
    size_t areg = (size_t)B * CAP * 4;                       // gEdges arena (12.8 MB)
    size_t h1sz = hreg > areg ? hreg : areg;
    size_t o = 0;
    int*      gcur  = (int*)(wsb + o);      o = align512(o + (size_t)BMAX * 4);
    int*      rbeg  = (int*)(wsb + o);      o = align512(o + (size_t)N * 4);
    int*      rendp = (int*)(wsb + o);      o = align512(o + (size_t)N * 4);
    float*    dis   = (float*)(wsb + o);    o = align512(o + (size_t)N * 4);
    int*      esrcA = (int*)(wsb + o);      o = align512(o + areg);
    _Float16* h1    = (_Float16*)(wsb + o); o = align512(o + h1sz);
    _Float16* agg1  = (_Float16*)(wsb + o); o = align512(o + (size_t)N * 128 * 2);
    _Float16* h2    = (_Float16*)(wsb + o); o = align512(o + (size_t)N * 64 * 2);
    size_t need = o;
    unsigned* gEdges = (unsigned*)h1;       // aliases h1 (dead before linear1)

    if (ws_size >= need && B <= BMAX) {
        // ---- build (single-pass arena) ----
        init_gcur_kernel<<<(B + 1023) / 1024, 1024, 0, stream>>>(gcur, B);
        bucket_scatter_kernel<<<(E + CHUNK - 1) / CHUNK, 256, 0, stream>>>(
            src, dst, gcur, gEdges, E, B);
        finalize_kernel<<<B, 256, 0, stream>>>(gEdges, gcur, rbeg, rendp, dis, esrcA, N);

        // ---- layer 1 transform: h1' = dis[n]*(x@W1^T+b1) (f16) ----
        linear1_kernel<<<512, 256, 0, stream>>>(x, W1, b1, dis, h1, N);
        // ---- layer 1 aggregate: agg1 = relu(dis[d]*sum h1'[src]) (f16) ----
        aggregate128h_kernel<<<(N + 15) / 16, 256, 0, stream>>>(h1, rbeg, rendp,
                                                                esrcA, dis, agg1, N);
        // ---- layer 2 transform: h2' = dis[n]*(agg1@W2^T+b2) (f16) ----
        lin2_kernel<<<512, 256, 0, stream>>>(agg1, W2, b2, dis, h2, N);
        // ---- layer 2 aggregate: out = dis[d]*sum h2'[src] (f32) ----
        aggregate64h_kernel<<<(N + 31) / 32, 256, 0, stream>>>(h2, rbeg, rendp,
                                                               esrcA, dis, out, N);
    } else {
        // =================== fallback: atomic path (f32) ===================
        float* deg  = (float*)wsb;
        size_t off  = align512((size_t)N * 4);
        float* fh1  = (float*)(wsb + off);
        float* fagg = fh1 + (size_t)N * FIN;
        float* fh2  = fh1;

        hipMemsetAsync(deg,  0, (size_t)N * 4, stream);
        hipMemsetAsync(fagg, 0, (size_t)N * FIN * 4, stream);
        hipMemsetAsync(out,  0, (size_t)N * 64 * 4, stream);

        deg_kernel_f<<<2048, 256, 0, stream>>>(dst, deg, E);
        dis_inplace_kernel<<<(N + 255) / 256, 256, 0, stream>>>(deg, N);

        linear_kernel<128, false><<<512, 256, 0, stream>>>(x, W1, b1, fh1, N);
        scatter_kernel<7><<<8192, 256, 0, stream>>>(fh1, src, dst, deg, fagg, E);
        linear_kernel<64, true><<<512, 256, 0, stream>>>(fagg, W2, b2, fh2, N);
        scatter_kernel<6><<<8192, 256, 0, stream>>>(fh2, src, dst, deg, out, E);
    }
}

// Round 9
// 173.795 us; speedup vs baseline: 1.1669x; 1.1669x over previous
//
#include <hip/hip_runtime.h>

constexpr int FIN    = 128;
constexpr int LOG_RB = 7;
constexpr int RB     = 1 << LOG_RB;   // 128 nodes per bucket
constexpr int BMAX   = 1024;
constexpr int CAP    = 4096;          // arena slots per bucket (avg ~2046, sd ~45)
constexpr int CHUNK  = 4096;          // edges per bucket_scatter block (r5/r7 proven)
constexpr int EPT    = CHUNK / 256;   // 16 edges per thread

typedef _Float16 half8 __attribute__((ext_vector_type(8)));
typedef float    f32x4 __attribute__((ext_vector_type(4)));

// ================= arena init: gcur[b] = b*CAP =================
__global__ __launch_bounds__(1024) void init_gcur_kernel(int* __restrict__ gcur, int B) {
    int i = blockIdx.x * 1024 + threadIdx.x;
    if (i < B) gcur[i] = i * CAP;
}

// ====== bucket scatter into per-bucket arena, RANK-CAPTURE (1 atomic pass) ==
__global__ __launch_bounds__(256) void bucket_scatter_kernel(
    const int* __restrict__ src, const int* __restrict__ dst,
    int* __restrict__ gcur, unsigned* __restrict__ gEdges, int E, int B)
{
    __shared__ int lhist[BMAX];
    __shared__ int lbase[BMAX];
    const int e0 = blockIdx.x * CHUNK;
    const int e1 = min(e0 + CHUNK, E);
    for (int i = threadIdx.x; i < B; i += 256) lhist[i] = 0;
    __syncthreads();

    int dreg[EPT];
    int rank[EPT];
    #pragma unroll
    for (int k = 0; k < EPT; ++k) {
        int e = e0 + k * 256 + threadIdx.x;
        dreg[k] = (e < e1) ? dst[e] : -1;
        rank[k] = (dreg[k] >= 0) ? atomicAdd(&lhist[dreg[k] >> LOG_RB], 1) : 0;
    }
    __syncthreads();
    for (int i = threadIdx.x; i < B; i += 256) {
        int c = lhist[i];
        if (c) lbase[i] = atomicAdd(&gcur[i], c);
    }
    __syncthreads();
    #pragma unroll
    for (int k = 0; k < EPT; ++k) {
        if (dreg[k] >= 0) {
            int e = e0 + k * 256 + threadIdx.x;
            int b = dreg[k] >> LOG_RB;
            int pos = lbase[b] + rank[k];
            if (pos < (b + 1) * CAP)   // capacity clamp (never hit: load << CAP)
                gEdges[pos] = ((unsigned)src[e] << LOG_RB) | (unsigned)(dreg[k] & (RB - 1));
        }
    }
}

// ====== finalize: per bucket -> rbeg/rend, dis, esrc (LDS stage + rank) =====
__global__ __launch_bounds__(256) void finalize_kernel(
    const unsigned* __restrict__ gEdges, const int* __restrict__ gcur,
    int* __restrict__ rbeg, int* __restrict__ rend, float* __restrict__ dis,
    int* __restrict__ esrc, int N)
{
    __shared__ int h[RB];
    __shared__ int excl[RB];
    __shared__ unsigned sedge[CAP];   // 16 KB
    __shared__ short    srank[CAP];   // 8 KB (rank < CAP=4096)
    const int b = blockIdx.x;
    const int base = b * CAP;
    int cnt = gcur[b] - base;
    if (cnt > CAP) cnt = CAP;
    const int node0 = b << LOG_RB;
    if (threadIdx.x < RB) h[threadIdx.x] = 0;
    __syncthreads();
    // single pass: stage edges + histogram with rank capture
    for (int i = threadIdx.x; i < cnt; i += 256) {
        unsigned p = gEdges[base + i];
        sedge[i] = p;
        srank[i] = (short)atomicAdd(&h[p & (RB - 1)], 1);
    }
    __syncthreads();
    if (threadIdx.x < RB) excl[threadIdx.x] = h[threadIdx.x];
    __syncthreads();
    for (int off = 1; off < RB; off <<= 1) {
        int u = 0;
        if (threadIdx.x < RB && threadIdx.x >= off) u = excl[threadIdx.x - off];
        __syncthreads();
        if (threadIdx.x < RB) excl[threadIdx.x] += u;
        __syncthreads();
    }
    if (threadIdx.x < RB) {
        int c  = h[threadIdx.x];
        int ex = excl[threadIdx.x] - c;   // exclusive
        int node = node0 + threadIdx.x;
        if (node < N) {
            rbeg[node] = base + ex;
            rend[node] = base + ex + c;
            dis[node]  = c > 0 ? rsqrtf((float)c) : 0.0f;
        }
        excl[threadIdx.x] = ex;           // overwrite with exclusive for placement
    }
    __syncthreads();
    // placement: no atomics
    for (int i = threadIdx.x; i < cnt; i += 256) {
        unsigned p = sedge[i];
        int dl = (int)(p & (RB - 1));
        esrc[base + excl[dl] + (int)srank[i]] = (int)(p >> LOG_RB);
    }
}

// ====== linear1: h1(f16) = dis[n]*(X(f32) @ W1^T + b1), MFMA, packed stores =
__global__ __launch_bounds__(256) void linear1_kernel(
    const float* __restrict__ X, const float* __restrict__ W,
    const float* __restrict__ Bv, const float* __restrict__ dis,
    _Float16* __restrict__ Y, int N)
{
    __shared__ __align__(16) _Float16 xs[64 * 128];   // 16 KB
    const int tid  = threadIdx.x;
    const int wave = tid >> 6;
    const int lane = tid & 63;
    const int l15  = lane & 15;
    const int lhi  = lane >> 4;

    half8 wf[2][4];
    float bias[2];
    #pragma unroll
    for (int c = 0; c < 2; ++c) {
        int f = (wave * 2 + c) * 16 + l15;
        #pragma unroll
        for (int ks = 0; ks < 4; ++ks) {
            const float* wp = &W[f * 128 + ks * 32 + lhi * 8];
            float4 u0 = *(const float4*)wp;
            float4 u1 = *(const float4*)(wp + 4);
            half8 hh;
            hh[0] = (_Float16)u0.x; hh[1] = (_Float16)u0.y;
            hh[2] = (_Float16)u0.z; hh[3] = (_Float16)u0.w;
            hh[4] = (_Float16)u1.x; hh[5] = (_Float16)u1.y;
            hh[6] = (_Float16)u1.z; hh[7] = (_Float16)u1.w;
            wf[c][ks] = hh;
        }
        bias[c] = Bv[f];
    }

    const int nchunks = (N + 63) / 64;
    for (int ch = blockIdx.x; ch < nchunks; ch += gridDim.x) {
        const int n0 = ch * 64;
        __syncthreads();
        #pragma unroll
        for (int p = 0; p < 4; ++p) {
            int ci  = p * 256 + tid;
            int row = ci >> 4, c = ci & 15;
            int n   = n0 + row;
            int nc  = n < N ? n : N - 1;
            const float* xp = &X[(size_t)nc * 128 + c * 8];
            float4 u0 = *(const float4*)xp;
            float4 u1 = *(const float4*)(xp + 4);
            half8 hh;
            hh[0] = (_Float16)u0.x; hh[1] = (_Float16)u0.y;
            hh[2] = (_Float16)u0.z; hh[3] = (_Float16)u0.w;
            hh[4] = (_Float16)u1.x; hh[5] = (_Float16)u1.y;
            hh[6] = (_Float16)u1.z; hh[7] = (_Float16)u1.w;
            *(half8*)&xs[row * 128 + (c ^ (row & 7)) * 8] = hh;
        }
        __syncthreads();

        f32x4 acc[4][2];
        #pragma unroll
        for (int mt = 0; mt < 4; ++mt)
            #pragma unroll
            for (int c = 0; c < 2; ++c) {
                acc[mt][c][0] = bias[c]; acc[mt][c][1] = bias[c];
                acc[mt][c][2] = bias[c]; acc[mt][c][3] = bias[c];
            }

        #pragma unroll
        for (int mt = 0; mt < 4; ++mt) {
            int row = mt * 16 + l15;
            #pragma unroll
            for (int ks = 0; ks < 4; ++ks) {
                int c  = ks * 4 + lhi;
                half8 a = *(const half8*)&xs[row * 128 + (c ^ (row & 7)) * 8];
                #pragma unroll
                for (int c2 = 0; c2 < 2; ++c2)
                    acc[mt][c2] = __builtin_amdgcn_mfma_f32_16x16x32_f16(
                        a, wf[c2][ks], acc[mt][c2], 0, 0, 0);
            }
        }
        __syncthreads();   // xs reads done; repack output into xs (linear)
        #pragma unroll
        for (int mt = 0; mt < 4; ++mt)
            #pragma unroll
            for (int r = 0; r < 4; ++r) {
                int row = mt * 16 + lhi * 4 + r;
                int n   = n0 + row;
                int nc  = n < N ? n : N - 1;
                float dv = dis[nc];
                #pragma unroll
                for (int c2 = 0; c2 < 2; ++c2) {
                    int col = (wave * 2 + c2) * 16 + l15;
                    xs[row * 128 + col] = (_Float16)(dv * acc[mt][c2][r]);
                }
            }
        __syncthreads();
        #pragma unroll
        for (int p = 0; p < 4; ++p) {
            int ci  = p * 256 + tid;
            int row = ci >> 4, c = ci & 15;
            int n   = n0 + row;
            if (n < N)
                *(half8*)&Y[(size_t)n * 128 + c * 8] = *(const half8*)&xs[row * 128 + c * 8];
        }
    }
}

// ====== layer-1 aggregate: agg1(f16) = relu(dis[d]*sum h1'[src]) ============
__global__ __launch_bounds__(256) void aggregate128h_kernel(
    const _Float16* __restrict__ H, const int* __restrict__ rbeg,
    const int* __restrict__ rend, const int* __restrict__ esrc,
    const float* __restrict__ dis, _Float16* __restrict__ OUT, int N)
{
    const int lane = threadIdx.x & 15;
    const int d = blockIdx.x * 16 + (threadIdx.x >> 4);
    if (d >= N) return;
    const int beg = rbeg[d], end = rend[d];
    float acc[4][8];
    #pragma unroll
    for (int u = 0; u < 4; ++u)
        #pragma unroll
        for (int j = 0; j < 8; ++j) acc[u][j] = 0.0f;

    const int n4 = (end - beg) >> 2;
    int e = beg;
    if (n4 > 0) {
        int s0 = esrc[e], s1 = esrc[e+1], s2 = esrc[e+2], s3 = esrc[e+3];
        for (int q = 1; q < n4; ++q) {
            const int b2 = beg + q * 4;
            int t0 = esrc[b2], t1 = esrc[b2+1], t2 = esrc[b2+2], t3 = esrc[b2+3];
            half8 v0 = *(const half8*)&H[(size_t)s0 * 128 + lane * 8];
            half8 v1 = *(const half8*)&H[(size_t)s1 * 128 + lane * 8];
            half8 v2 = *(const half8*)&H[(size_t)s2 * 128 + lane * 8];
            half8 v3 = *(const half8*)&H[(size_t)s3 * 128 + lane * 8];
            #pragma unroll
            for (int j = 0; j < 8; ++j) {
                acc[0][j] += (float)v0[j]; acc[1][j] += (float)v1[j];
                acc[2][j] += (float)v2[j]; acc[3][j] += (float)v3[j];
            }
            s0 = t0; s1 = t1; s2 = t2; s3 = t3;
        }
        {
            half8 v0 = *(const half8*)&H[(size_t)s0 * 128 + lane * 8];
            half8 v1 = *(const half8*)&H[(size_t)s1 * 128 + lane * 8];
            half8 v2 = *(const half8*)&H[(size_t)s2 * 128 + lane * 8];
            half8 v3 = *(const half8*)&H[(size_t)s3 * 128 + lane * 8];
            #pragma unroll
            for (int j = 0; j < 8; ++j) {
                acc[0][j] += (float)v0[j]; acc[1][j] += (float)v1[j];
                acc[2][j] += (float)v2[j]; acc[3][j] += (float)v3[j];
            }
        }
        e = beg + n4 * 4;
    }
    for (; e < end; ++e) {
        int s0 = esrc[e];
        half8 v0 = *(const half8*)&H[(size_t)s0 * 128 + lane * 8];
        #pragma unroll
        for (int j = 0; j < 8; ++j) acc[0][j] += (float)v0[j];
    }
    float w = dis[d];
    half8 o;
    #pragma unroll
    for (int j = 0; j < 8; ++j) {
        float t = w * ((acc[0][j] + acc[1][j]) + (acc[2][j] + acc[3][j]));
        o[j] = (_Float16)fmaxf(t, 0.0f);          // relu
    }
    *(half8*)&OUT[(size_t)d * 128 + lane * 8] = o;
}

// ====== lin2: h2(f16) = dis[n]*(agg1(f16) @ W2^T + b2), MFMA, packed stores =
__global__ __launch_bounds__(256) void lin2_kernel(
    const _Float16* __restrict__ Xh, const float* __restrict__ W,
    const float* __restrict__ Bv, const float* __restrict__ dis,
    _Float16* __restrict__ Y, int N)
{
    __shared__ __align__(16) _Float16 xs[64 * 128];   // 16 KB in, 8 KB reused out
    const int tid  = threadIdx.x;
    const int wave = tid >> 6;
    const int lane = tid & 63;
    const int l15  = lane & 15;
    const int lhi  = lane >> 4;

    half8 wf[4];
    float bias;
    {
        int f = wave * 16 + l15;
        #pragma unroll
        for (int ks = 0; ks < 4; ++ks) {
            const float* wp = &W[f * 128 + ks * 32 + lhi * 8];
            float4 u0 = *(const float4*)wp;
            float4 u1 = *(const float4*)(wp + 4);
            half8 hh;
            hh[0] = (_Float16)u0.x; hh[1] = (_Float16)u0.y;
            hh[2] = (_Float16)u0.z; hh[3] = (_Float16)u0.w;
            hh[4] = (_Float16)u1.x; hh[5] = (_Float16)u1.y;
            hh[6] = (_Float16)u1.z; hh[7] = (_Float16)u1.w;
            wf[ks] = hh;
        }
        bias = Bv[f];
    }

    const int nchunks = (N + 63) / 64;
    for (int ch = blockIdx.x; ch < nchunks; ch += gridDim.x) {
        const int n0 = ch * 64;
        __syncthreads();
        #pragma unroll
        for (int p = 0; p < 4; ++p) {
            int ci  = p * 256 + tid;
            int row = ci >> 4, c = ci & 15;
            int n   = n0 + row;
            int nc  = n < N ? n : N - 1;
            half8 hh = *(const half8*)&Xh[(size_t)nc * 128 + c * 8];
            *(half8*)&xs[row * 128 + (c ^ (row & 7)) * 8] = hh;
        }
        __syncthreads();

        f32x4 acc[4];
        #pragma unroll
        for (int mt = 0; mt < 4; ++mt) {
            acc[mt][0] = bias; acc[mt][1] = bias;
            acc[mt][2] = bias; acc[mt][3] = bias;
        }
        #pragma unroll
        for (int mt = 0; mt < 4; ++mt) {
            int row = mt * 16 + l15;
            #pragma unroll
            for (int ks = 0; ks < 4; ++ks) {
                int c  = ks * 4 + lhi;
                half8 a = *(const half8*)&xs[row * 128 + (c ^ (row & 7)) * 8];
                acc[mt] = __builtin_amdgcn_mfma_f32_16x16x32_f16(a, wf[ks], acc[mt], 0, 0, 0);
            }
        }
        __syncthreads();   // reuse xs as [64][64] output tile
        #pragma unroll
        for (int mt = 0; mt < 4; ++mt)
            #pragma unroll
            for (int r = 0; r < 4; ++r) {
                int row = mt * 16 + lhi * 4 + r;
                int n   = n0 + row;
                int nc  = n < N ? n : N - 1;
                float dv = dis[nc];
                xs[row * 64 + wave * 16 + l15] = (_Float16)(dv * acc[mt][r]);
            }
        __syncthreads();
        #pragma unroll
        for (int p = 0; p < 2; ++p) {
            int ci  = p * 256 + tid;
            int row = ci >> 3, c = ci & 7;
            int n   = n0 + row;
            if (n < N)
                *(half8*)&Y[(size_t)n * 64 + c * 8] = *(const half8*)&xs[row * 64 + c * 8];
        }
    }
}

// ====== layer-2 aggregate: out(f32) = dis[d]*sum h2'[src], pipelined ========
__global__ __launch_bounds__(256) void aggregate64h_kernel(
    const _Float16* __restrict__ H, const int* __restrict__ rbeg,
    const int* __restrict__ rend, const int* __restrict__ esrc,
    const float* __restrict__ dis, float* __restrict__ OUT, int N)
{
    const int lane = threadIdx.x & 7;
    const int d = blockIdx.x * 32 + (threadIdx.x >> 3);
    if (d >= N) return;
    const int beg = rbeg[d], end = rend[d];
    float acc[4][8];
    #pragma unroll
    for (int u = 0; u < 4; ++u)
        #pragma unroll
        for (int j = 0; j < 8; ++j) acc[u][j] = 0.0f;

    const int n4 = (end - beg) >> 2;
    int e = beg;
    if (n4 > 0) {
        int s0 = esrc[e], s1 = esrc[e+1], s2 = esrc[e+2], s3 = esrc[e+3];
        for (int q = 1; q < n4; ++q) {
            const int b2 = beg + q * 4;
            int t0 = esrc[b2], t1 = esrc[b2+1], t2 = esrc[b2+2], t3 = esrc[b2+3];
            half8 v0 = *(const half8*)&H[(size_t)s0 * 64 + lane * 8];
            half8 v1 = *(const half8*)&H[(size_t)s1 * 64 + lane * 8];
            half8 v2 = *(const half8*)&H[(size_t)s2 * 64 + lane * 8];
            half8 v3 = *(const half8*)&H[(size_t)s3 * 64 + lane * 8];
            #pragma unroll
            for (int j = 0; j < 8; ++j) {
                acc[0][j] += (float)v0[j]; acc[1][j] += (float)v1[j];
                acc[2][j] += (float)v2[j]; acc[3][j] += (float)v3[j];
            }
            s0 = t0; s1 = t1; s2 = t2; s3 = t3;
        }
        {
            half8 v0 = *(const half8*)&H[(size_t)s0 * 64 + lane * 8];
            half8 v1 = *(const half8*)&H[(size_t)s1 * 64 + lane * 8];
            half8 v2 = *(const half8*)&H[(size_t)s2 * 64 + lane * 8];
            half8 v3 = *(const half8*)&H[(size_t)s3 * 64 + lane * 8];
            #pragma unroll
            for (int j = 0; j < 8; ++j) {
                acc[0][j] += (float)v0[j]; acc[1][j] += (float)v1[j];
                acc[2][j] += (float)v2[j]; acc[3][j] += (float)v3[j];
            }
        }
        e = beg + n4 * 4;
    }
    for (; e < end; ++e) {
        int s0 = esrc[e];
        half8 v0 = *(const half8*)&H[(size_t)s0 * 64 + lane * 8];
        #pragma unroll
        for (int j = 0; j < 8; ++j) acc[0][j] += (float)v0[j];
    }
    float w = dis[d];
    float4 o0, o1;
    o0.x = w * ((acc[0][0] + acc[1][0]) + (acc[2][0] + acc[3][0]));
    o0.y = w * ((acc[0][1] + acc[1][1]) + (acc[2][1] + acc[3][1]));
    o0.z = w * ((acc[0][2] + acc[1][2]) + (acc[2][2] + acc[3][2]));
    o0.w = w * ((acc[0][3] + acc[1][3]) + (acc[2][3] + acc[3][3]));
    o1.x = w * ((acc[0][4] + acc[1][4]) + (acc[2][4] + acc[3][4]));
    o1.y = w * ((acc[0][5] + acc[1][5]) + (acc[2][5] + acc[3][5]));
    o1.z = w * ((acc[0][6] + acc[1][6]) + (acc[2][6] + acc[3][6]));
    o1.w = w * ((acc[0][7] + acc[1][7]) + (acc[2][7] + acc[3][7]));
    float* p = &OUT[(size_t)d * 64 + lane * 8];
    *(float4*)p = o0;
    *(float4*)(p + 4) = o1;
}

// ================= fallback path (round-1, f32 end-to-end) ==================
template <int FOUT, bool RELU_IN>
__global__ __launch_bounds__(256) void linear_kernel(
    const float* __restrict__ X, const float* __restrict__ W,
    const float* __restrict__ Bv, float* __restrict__ Y, int N)
{
    constexpr int TX = FOUT / 4;
    constexpr int TY = 256 / TX;
    constexpr int NB = 4 * TY;
    constexpr int QMASK = TX - 1;
    __shared__ float ws[FIN * FOUT];
    __shared__ float xs[NB * FIN];
    const int tid = threadIdx.x;
    const int tx  = tid % TX;
    const int ty  = tid / TX;
    for (int i = tid; i < FOUT * FIN; i += 256) {
        int f = i >> 7;
        int k = i & (FIN - 1);
        int q = f >> 2, r = f & 3;
        int qq = q ^ (k & QMASK);
        ws[k * FOUT + qq * 4 + r] = W[i];
    }
    const float4 bv = *(const float4*)&Bv[tx * 4];
    const int nchunks = (N + NB - 1) / NB;
    for (int c = blockIdx.x; c < nchunks; c += gridDim.x) {
        const int n0 = c * NB;
        __syncthreads();
        constexpr int V4 = FIN / 4;
        for (int i4 = tid; i4 < NB * V4; i4 += 256) {
            int row = i4 / V4, c4 = i4 % V4;
            int n = n0 + row;
            int nc = n < N ? n : N - 1;
            float4 v = *(const float4*)&X[(long long)nc * FIN + c4 * 4];
            if (RELU_IN) {
                v.x = fmaxf(v.x, 0.0f); v.y = fmaxf(v.y, 0.0f);
                v.z = fmaxf(v.z, 0.0f); v.w = fmaxf(v.w, 0.0f);
            }
            *(float4*)&xs[row * FIN + c4 * 4] = v;
        }
        __syncthreads();
        float acc[4][4];
        #pragma unroll
        for (int j = 0; j < 4; ++j) {
            acc[j][0] = bv.x; acc[j][1] = bv.y; acc[j][2] = bv.z; acc[j][3] = bv.w;
        }
        #pragma unroll 2
        for (int k = 0; k < FIN; k += 4) {
            float w[4][4];
            #pragma unroll
            for (int kk = 0; kk < 4; ++kk) {
                int kr = k + kk;
                float4 t = *(const float4*)&ws[kr * FOUT + ((tx ^ (kr & QMASK)) << 2)];
                w[kk][0] = t.x; w[kk][1] = t.y; w[kk][2] = t.z; w[kk][3] = t.w;
            }
            float xr[4][4];
            #pragma unroll
            for (int j = 0; j < 4; ++j) {
                float4 t = *(const float4*)&xs[(ty * 4 + j) * FIN + k];
                xr[j][0] = t.x; xr[j][1] = t.y; xr[j][2] = t.z; xr[j][3] = t.w;
            }
            #pragma unroll
            for (int j = 0; j < 4; ++j)
                #pragma unroll
                for (int kk = 0; kk < 4; ++kk) {
                    acc[j][0] = fmaf(xr[j][kk], w[kk][0], acc[j][0]);
                    acc[j][1] = fmaf(xr[j][kk], w[kk][1], acc[j][1]);
                    acc[j][2] = fmaf(xr[j][kk], w[kk][2], acc[j][2]);
                    acc[j][3] = fmaf(xr[j][kk], w[kk][3], acc[j][3]);
                }
        }
        #pragma unroll
        for (int j = 0; j < 4; ++j) {
            int n = n0 + ty * 4 + j;
            if (n < N) {
                float4 o;
                o.x = acc[j][0]; o.y = acc[j][1]; o.z = acc[j][2]; o.w = acc[j][3];
                *(float4*)&Y[(long long)n * FOUT + tx * 4] = o;
            }
        }
    }
}

template <int LOGF>
__global__ __launch_bounds__(256) void scatter_kernel(
    const float* __restrict__ H, const int* __restrict__ src,
    const int* __restrict__ dst, const float* __restrict__ dis,
    float* __restrict__ OUT, int E)
{
    constexpr int F = 1 << LOGF;
    const long long total  = (long long)E << LOGF;
    const long long stride = (long long)gridDim.x * blockDim.x;
    for (long long i = (long long)blockIdx.x * blockDim.x + threadIdx.x;
         i < total; i += stride) {
        int e = (int)(i >> LOGF);
        int f = (int)i & (F - 1);
        int s = src[e];
        int d = dst[e];
        float w = dis[s] * dis[d];
        atomicAdd(&OUT[d * F + f], w * H[s * F + f]);
    }
}

__global__ __launch_bounds__(256) void dis_inplace_kernel(float* __restrict__ deg, int N) {
    int i = blockIdx.x * 256 + threadIdx.x;
    if (i < N) {
        float d = deg[i];
        deg[i] = d > 0.0f ? rsqrtf(d) : 0.0f;
    }
}

__global__ __launch_bounds__(256) void deg_kernel_f(const int* __restrict__ dst,
                                                    float* __restrict__ deg, int E) {
    int stride = gridDim.x * 256;
    for (int i = blockIdx.x * 256 + threadIdx.x; i < E; i += stride)
        atomicAdd(&deg[dst[i]], 1.0f);
}

static inline size_t align512(size_t x) { return (x + 511) & ~(size_t)511; }

extern "C" void kernel_launch(void* const* d_in, const int* in_sizes, int n_in,
                              void* d_out, int out_size, void* d_ws, size_t ws_size,
                              hipStream_t stream)
{
    const float* x  = (const float*)d_in[0];
    const int*   ei = (const int*)d_in[1];
    const float* W1 = (const float*)d_in[2];
    const float* b1 = (const float*)d_in[3];
    const float* W2 = (const float*)d_in[4];
    const float* b2 = (const float*)d_in[5];

    const int N = in_sizes[0] / FIN;     // 100000
    const int E = in_sizes[1] / 2;       // 1600000
    const int* src = ei;
    const int* dst = ei + E;
    float* out = (float*)d_out;
    char* wsb = (char*)d_ws;

    const int B = (N + RB - 1) / RB;     // 782

    // ---- workspace layout ----
    size_t hreg = (size_t)N * 128 * 2;                       // h1 region (fp16)
    size_t areg = (size_t)B * CAP * 4;                       // gEdges arena (12.8 MB)
    size_t h1sz = hreg > areg ? hreg : areg;
    size_t o = 0;
    int*      gcur  = (int*)(wsb + o);      o = align512(o + (size_t)BMAX * 4);
    int*      rbeg  = (int*)(wsb + o);      o = align512(o + (size_t)N * 4);
    int*      rendp = (int*)(wsb + o);      o = align512(o + (size_t)N * 4);
    float*    dis   = (float*)(wsb + o);    o = align512(o + (size_t)N * 4);
    int*      esrcA = (int*)(wsb + o);      o = align512(o + areg);
    _Float16* h1    = (_Float16*)(wsb + o); o = align512(o + h1sz);
    _Float16* agg1  = (_Float16*)(wsb + o); o = align512(o + (size_t)N * 128 * 2);
    _Float16* h2    = (_Float16*)(wsb + o); o = align512(o + (size_t)N * 64 * 2);
    size_t need = o;
    unsigned* gEdges = (unsigned*)h1;       // aliases h1 (dead before linear1)

    if (ws_size >= need && B <= BMAX) {
        // ---- build (single-pass arena, rank-capture) ----
        init_gcur_kernel<<<(B + 1023) / 1024, 1024, 0, stream>>>(gcur, B);
        bucket_scatter_kernel<<<(E + CHUNK - 1) / CHUNK, 256, 0, stream>>>(
            src, dst, gcur, gEdges, E, B);
        finalize_kernel<<<B, 256, 0, stream>>>(gEdges, gcur, rbeg, rendp, dis, esrcA, N);

        // ---- layer 1 transform: h1' = dis[n]*(x@W1^T+b1) (f16) ----
        linear1_kernel<<<512, 256, 0, stream>>>(x, W1, b1, dis, h1, N);
        // ---- layer 1 aggregate: agg1 = relu(dis[d]*sum h1'[src]) (f16) ----
        aggregate128h_kernel<<<(N + 15) / 16, 256, 0, stream>>>(h1, rbeg, rendp,
                                                                esrcA, dis, agg1, N);
        // ---- layer 2 transform: h2' = dis[n]*(agg1@W2^T+b2) (f16) ----
        lin2_kernel<<<512, 256, 0, stream>>>(agg1, W2, b2, dis, h2, N);
        // ---- layer 2 aggregate: out = dis[d]*sum h2'[src] (f32) ----
        aggregate64h_kernel<<<(N + 31) / 32, 256, 0, stream>>>(h2, rbeg, rendp,
                                                               esrcA, dis, out, N);
    } else {
        // =================== fallback: atomic path (f32) ===================
        float* deg  = (float*)wsb;
        size_t off  = align512((size_t)N * 4);
        float* fh1  = (float*)(wsb + off);
        float* fagg = fh1 + (size_t)N * FIN;
        float* fh2  = fh1;

        hipMemsetAsync(deg,  0, (size_t)N * 4, stream);
        hipMemsetAsync(fagg, 0, (size_t)N * FIN * 4, stream);
        hipMemsetAsync(out,  0, (size_t)N * 64 * 4, stream);

        deg_kernel_f<<<2048, 256, 0, stream>>>(dst, deg, E);
        dis_inplace_kernel<<<(N + 255) / 256, 256, 0, stream>>>(deg, N);

        linear_kernel<128, false><<<512, 256, 0, stream>>>(x, W1, b1, fh1, N);
        scatter_kernel<7><<<8192, 256, 0, stream>>>(fh1, src, dst, deg, fagg, E);
        linear_kernel<64, true><<<512, 256, 0, stream>>>(fagg, W2, b2, fh2, N);
        scatter_kernel<6><<<8192, 256, 0, stream>>>(fh2, src, dst, deg, out, E);
    }
}